// Round 13
// baseline (57.370 us; speedup 1.0000x reference)
//
#include <hip/hip_runtime.h>
#include <hip/hip_bf16.h>

#define BB 4
#define CC 64
#define HH 256
#define WW 256
#define KK 9
#define NOFF 18
#define HO 254
#define WO 254
#define NPIX (HO*WO)           // 64516

typedef __attribute__((ext_vector_type(8))) short bf16x8;
typedef __attribute__((ext_vector_type(4))) float f32x4;

// ---- cacheable device-global storage (NOT d_ws: ws appears to be uncached) ----
__device__ __align__(16) unsigned char  g_wpack[22784];
__device__ __align__(16) unsigned short g_xT[(size_t)BB * HH * WW * CC];   // 33.5 MB

static __device__ __forceinline__ unsigned short f2bf(float v) {
    __hip_bfloat16 h = __float2bfloat16(v);
    union { __hip_bfloat16 b; unsigned short u; } cv; cv.b = h; return cv.u;
}
static __device__ __forceinline__ float bf2f(unsigned short u) {
    unsigned int w = ((unsigned int)u) << 16;
    float f; __builtin_memcpy(&f, &w, 4); return f;
}

static __device__ __forceinline__ void repack_piece(
    int tap, int tid, int nthr,
    const float* __restrict__ offset_w,
    const float* __restrict__ deform_w)
{
    if (tap < 9) {
        for (int i = tid; i < 18 * 64; i += nthr) {
            int o = i >> 6;
            int c = i & 63;
            int row = tap * 18 + o;
            unsigned int byte = (unsigned)(row * 128 + c * 2) ^ (((unsigned)(row & 7)) << 4);
            *(unsigned short*)(g_wpack + byte) = f2bf(offset_w[((size_t)o * CC + c) * KK + tap]);
        }
    } else {
        for (int i = tid; i < 16 * 64; i += nthr) {
            int t = i >> 6;
            int c = i & 63;
            float v = (t < KK) ? deform_w[(size_t)c * KK + t] : 0.0f;
            unsigned int byte = (unsigned)(t * 128 + c * 2) ^ (((unsigned)(t & 7)) << 4);
            *(unsigned short*)(g_wpack + 20736 + byte) = f2bf(v);
        }
    }
}

// ========== kernel P: x NCHW f32 -> g_xT NHWC bf16 (+ fused weight repack) ==========
__global__ __launch_bounds__(256) void transpose_kernel(
    const float* __restrict__ x,
    const float* __restrict__ offset_w,
    const float* __restrict__ deform_w)
{
    __shared__ float s[64][65];
    const int tid = threadIdx.x;
    const int w0 = blockIdx.x * 64;
    const int h  = blockIdx.y;
    const int b  = blockIdx.z;

    if (b == 0 && blockIdx.x == 0 && h < 10)
        repack_piece(h, tid, 256, offset_w, deform_w);

    #pragma unroll
    for (int it = 0; it < 4; ++it) {
        int i  = tid + it * 256;
        int c  = i >> 4;
        int p4 = (i & 15) << 2;
        float4 v = *(const float4*)(x + (((size_t)b * CC + c) * HH + h) * WW + w0 + p4);
        s[c][p4 + 0] = v.x; s[c][p4 + 1] = v.y; s[c][p4 + 2] = v.z; s[c][p4 + 3] = v.w;
    }
    __syncthreads();
    #pragma unroll
    for (int it = 0; it < 2; ++it) {
        int j  = tid + it * 256;
        int px = j >> 3;
        int g  = j & 7;
        unsigned int u[4];
        #pragma unroll
        for (int q = 0; q < 4; ++q) {
            __hip_bfloat162 h2 = __float22bfloat162_rn(
                make_float2(s[g * 8 + 2 * q][px], s[g * 8 + 2 * q + 1][px]));
            __builtin_memcpy(&u[q], &h2, 4);
        }
        unsigned short* dst = g_xT + (((size_t)b * HH + h) * WW + w0 + px) * 64 + g * 8;
        *(uint4*)dst = make_uint4(u[0], u[1], u[2], u[3]);
    }
}

// ====== kernel F: fused conv + Y-ext + in-LDS gather (16x16 tile, 4 waves) ======
#define PTF 22
#define NCF 484     // 22*22
#define LDS_SOFF 0      // f32 [18][257] = 18504 B  (phase 2, aliases weights)
#define LDS_SY   18504  // f32 [9][485]  = 17460 B
#define SMEM_F   35968

__global__ __launch_bounds__(256) void conv_gather_fused(
    const float* __restrict__ offset_b,
    const float* __restrict__ deform_w,
    const float* __restrict__ deform_b,
    float* __restrict__ out)
{
    __shared__ __align__(16) unsigned char smem[SMEM_F];
    const int tid = threadIdx.x;

    {   // stage swizzled weights (22784 B) from cacheable device global
        const uint4* src = (const uint4*)g_wpack;
        uint4* dst = (uint4*)smem;
        for (int i = tid; i < 1424; i += 256) dst[i] = src[i];
    }
    __syncthreads();

    const int wv = tid >> 6;
    const int l  = tid & 63;
    const int lr = l & 15;
    const int lk = l >> 4;

    const int x0 = blockIdx.x * 16;
    const int y0 = blockIdx.y * 16;
    const int b  = blockIdx.z;
    const unsigned char* xb = (const unsigned char*)(g_xT + (size_t)b * HH * WW * 64);

    const int o1 = (16 + lr > 17) ? 17 : 16 + lr;
    const float bias0 = offset_b[lr];
    const float bias1 = (lr < 2) ? offset_b[16 + lr] : 0.0f;

    f32x4 accC[4][2];
    f32x4 accY[8];
    #pragma unroll
    for (int mi = 0; mi < 4; ++mi)
        #pragma unroll
        for (int reg = 0; reg < 4; ++reg) { accC[mi][0][reg] = bias0; accC[mi][1][reg] = bias1; }
    #pragma unroll
    for (int j = 0; j < 8; ++j) accY[j] = (f32x4){0.f, 0.f, 0.f, 0.f};

    auto ldw = [&](int row, int cbyte) -> bf16x8 {
        unsigned int byte = (unsigned)(row * 128 + cbyte) ^ (((unsigned)(row & 7)) << 4);
        return *(const bf16x8*)(smem + byte);
    };

    // ---------------- phase 1: MFMA (A-frags direct from g_xT) ----------------
    #pragma unroll
    for (int ch = 0; ch < 2; ++ch) {
        const int cbyte = ch * 64 + lk * 16;
        #pragma unroll
        for (int kw = 0; kw < 3; ++kw) {
            const int gx = min(x0 + lr + kw, WW - 1);
            bf16x8 a[6];
            #pragma unroll
            for (int rr = 0; rr < 6; ++rr) {
                const int gy = min(y0 + 4 * wv + rr, HH - 1);
                a[rr] = *(const bf16x8*)(xb + (size_t)(gy * WW + gx) * 128 + cbyte);
            }
            #pragma unroll
            for (int kh = 0; kh < 3; ++kh) {
                const int tap = kh * 3 + kw;
                bf16x8 b0 = ldw(tap * 18 + lr, cbyte);
                bf16x8 b1 = ldw(tap * 18 + o1, cbyte);
                #pragma unroll
                for (int mi = 0; mi < 4; ++mi) {
                    accC[mi][0] = __builtin_amdgcn_mfma_f32_16x16x32_bf16(a[mi + kh], b0, accC[mi][0], 0, 0, 0);
                    accC[mi][1] = __builtin_amdgcn_mfma_f32_16x16x32_bf16(a[mi + kh], b1, accC[mi][1], 0, 0, 0);
                }
            }
        }
        // Y-ext: 484 cells over 22x22 patch, 31 M-tiles, wave handles t = wv+4j
        {
            unsigned int byY = (unsigned)(lr * 128 + cbyte) ^ (((unsigned)(lr & 7)) << 4);
            bf16x8 bY = *(const bf16x8*)(smem + 20736 + byY);
            #pragma unroll
            for (int j = 0; j < 8; ++j) {
                const int t = wv + 4 * j;
                if (t < 31) {
                    int cell = t * 16 + lr; if (cell > NCF - 1) cell = NCF - 1;
                    int r = cell / PTF, col = cell - r * PTF;
                    int gy = min(max(y0 - 2 + r, 0), HH - 1);
                    int gx = min(max(x0 - 2 + col, 0), WW - 1);
                    bf16x8 a = *(const bf16x8*)(xb + (size_t)(gy * WW + gx) * 128 + cbyte);
                    accY[j] = __builtin_amdgcn_mfma_f32_16x16x32_bf16(a, bY, accY[j], 0, 0, 0);
                }
            }
        }
    }

    __syncthreads();   // all weight reads done; arena can be re-used

    // ---------------- phase 2: redistribute to LDS ----------------
    float* s_off = (float*)(smem + LDS_SOFF);   // [18][257]
    float* s_Y   = (float*)(smem + LDS_SY);     // [9][485]
    #pragma unroll
    for (int mi = 0; mi < 4; ++mi) {
        #pragma unroll
        for (int nt = 0; nt < 2; ++nt) {
            const int o = nt * 16 + lr;
            if (o < NOFF) {
                const int pbase = (4 * wv + mi) * 16 + lk * 4;
                #pragma unroll
                for (int reg = 0; reg < 4; ++reg)
                    s_off[o * 257 + pbase + reg] = accC[mi][nt][reg];
            }
        }
    }
    #pragma unroll
    for (int j = 0; j < 8; ++j) {
        const int t = wv + 4 * j;
        if (t < 31 && lr < KK) {
            #pragma unroll
            for (int reg = 0; reg < 4; ++reg) {
                const int cell = t * 16 + lk * 4 + reg;
                if (cell < NCF) {
                    int r = cell / PTF, col = cell - r * PTF;
                    int gy = y0 - 2 + r, gx = x0 - 2 + col;
                    bool inimg = (gy >= 0 && gy < HH && gx >= 0 && gx < WW);
                    s_Y[lr * 485 + cell] = inimg ? accY[j][reg] : 0.0f;
                }
            }
        }
    }
    __syncthreads();

    // ---------------- phase 3: in-LDS bilinear gather ----------------
    const int ty = tid >> 4, tx = tid & 15;
    const int ho = y0 + ty, wo = x0 + tx;
    if (ho >= HO || wo >= WO) return;

    float acc = deform_b[0];

    #pragma unroll
    for (int k = 0; k < KK; ++k) {
        const int kh = k / 3, kw = k % 3;
        float dy = s_off[(2 * k) * 257 + tid];
        float dx = s_off[(2 * k + 1) * 257 + tid];
        float py = (float)(ho + kh) + dy;
        float px = (float)(wo + kw) + dx;
        float y0f = floorf(py), x0f = floorf(px);
        float ly = py - y0f, lx = px - x0f;
        int yi0 = (int)y0f, xi0 = (int)x0f;
        int ry = yi0 - (y0 - 2);
        int rx = xi0 - (x0 - 2);
        float w00 = (1.0f - ly) * (1.0f - lx);
        float w01 = (1.0f - ly) * lx;
        float w10 = ly * (1.0f - lx);
        float w11 = ly * lx;
        float g;
        if ((unsigned)ry <= (unsigned)(PTF - 2) && (unsigned)rx <= (unsigned)(PTF - 2)) {
            // fast path: all 4 corners inside slack patch; out-of-image cells are 0
            const float* tp = s_Y + k * 485;
            const int id = ry * PTF + rx;
            g = w00 * tp[id]       + w01 * tp[id + 1]
              + w10 * tp[id + PTF] + w11 * tp[id + PTF + 1];
        } else {
            // rare fallback: exact bilinear over channels from g_xT
            int yi1 = yi0 + 1, xi1 = xi0 + 1;
            float m00 = (yi0 >= 0 && yi0 < HH && xi0 >= 0 && xi0 < WW) ? w00 : 0.0f;
            float m01 = (yi0 >= 0 && yi0 < HH && xi1 >= 0 && xi1 < WW) ? w01 : 0.0f;
            float m10 = (yi1 >= 0 && yi1 < HH && xi0 >= 0 && xi0 < WW) ? w10 : 0.0f;
            float m11 = (yi1 >= 0 && yi1 < HH && xi1 >= 0 && xi1 < WW) ? w11 : 0.0f;
            int y0c = min(max(yi0, 0), HH - 1), y1c = min(max(yi1, 0), HH - 1);
            int x0c = min(max(xi0, 0), WW - 1), x1c = min(max(xi1, 0), WW - 1);
            const unsigned short* p00 = (const unsigned short*)(xb + (size_t)(y0c * WW + x0c) * 128);
            const unsigned short* p01 = (const unsigned short*)(xb + (size_t)(y0c * WW + x1c) * 128);
            const unsigned short* p10 = (const unsigned short*)(xb + (size_t)(y1c * WW + x0c) * 128);
            const unsigned short* p11 = (const unsigned short*)(xb + (size_t)(y1c * WW + x1c) * 128);
            g = 0.0f;
            for (int c = 0; c < CC; ++c) {
                float gc = m00 * bf2f(p00[c]) + m01 * bf2f(p01[c])
                         + m10 * bf2f(p10[c]) + m11 * bf2f(p11[c]);
                g = fmaf(gc, deform_w[(size_t)c * KK + k], g);
            }
        }
        acc += g;
    }

    out[(size_t)b * NPIX + ho * WO + wo] = acc;
}

extern "C" void kernel_launch(void* const* d_in, const int* in_sizes, int n_in,
                              void* d_out, int out_size, void* d_ws, size_t ws_size,
                              hipStream_t stream) {
    const float* x        = (const float*)d_in[0];
    const float* offset_w = (const float*)d_in[1];
    const float* offset_b = (const float*)d_in[2];
    const float* deform_w = (const float*)d_in[3];
    const float* deform_b = (const float*)d_in[4];
    float* out = (float*)d_out;

    // stage 1: transpose x into cacheable device-global xT (+ one-time weight repack)
    hipLaunchKernelGGL(transpose_kernel, dim3(4, 256, BB), dim3(256), 0, stream,
                       x, offset_w, deform_w);
    // stage 2: fused offset-conv + Y channel-collapse + in-LDS bilinear gather
    hipLaunchKernelGGL(conv_gather_fused, dim3(16, 16, BB), dim3(256), 0, stream,
                       offset_b, deform_w, deform_b, out);
}

// Round 14
// 56.910 us; speedup vs baseline: 1.0081x; 1.0081x over previous
//
#include <hip/hip_runtime.h>
#include <hip/hip_bf16.h>

#define BB 4
#define CC 64
#define HH 256
#define WW 256
#define KK 9
#define NOFF 18
#define HO 254
#define WO 254
#define NPIX (HO*WO)           // 64516

typedef __attribute__((ext_vector_type(8))) short bf16x8;
typedef __attribute__((ext_vector_type(4))) float f32x4;

// ---- cacheable device-global storage ----
__device__ __align__(16) unsigned char  g_wpack[22784];
__device__ __align__(16) unsigned short g_xT[(size_t)BB * HH * WW * CC];   // 33.5 MB

static __device__ __forceinline__ unsigned short f2bf(float v) {
    __hip_bfloat16 h = __float2bfloat16(v);
    union { __hip_bfloat16 b; unsigned short u; } cv; cv.b = h; return cv.u;
}
static __device__ __forceinline__ float bf2f(unsigned short u) {
    unsigned int w = ((unsigned int)u) << 16;
    float f; __builtin_memcpy(&f, &w, 4); return f;
}

static __device__ __forceinline__ void repack_piece(
    int tap, int tid, int nthr,
    const float* __restrict__ offset_w,
    const float* __restrict__ deform_w)
{
    if (tap < 9) {
        for (int i = tid; i < 18 * 64; i += nthr) {
            int o = i >> 6;
            int c = i & 63;
            int row = tap * 18 + o;
            unsigned int byte = (unsigned)(row * 128 + c * 2) ^ (((unsigned)(row & 7)) << 4);
            *(unsigned short*)(g_wpack + byte) = f2bf(offset_w[((size_t)o * CC + c) * KK + tap]);
        }
    } else {
        for (int i = tid; i < 16 * 64; i += nthr) {
            int t = i >> 6;
            int c = i & 63;
            float v = (t < KK) ? deform_w[(size_t)c * KK + t] : 0.0f;
            unsigned int byte = (unsigned)(t * 128 + c * 2) ^ (((unsigned)(t & 7)) << 4);
            *(unsigned short*)(g_wpack + 20736 + byte) = f2bf(v);
        }
    }
}

// ========== kernel P: x NCHW f32 -> g_xT NHWC bf16 (+ fused weight repack) ==========
__global__ __launch_bounds__(256) void transpose_kernel(
    const float* __restrict__ x,
    const float* __restrict__ offset_w,
    const float* __restrict__ deform_w)
{
    __shared__ float s[64][65];
    const int tid = threadIdx.x;
    const int w0 = blockIdx.x * 64;
    const int h  = blockIdx.y;
    const int b  = blockIdx.z;

    if (b == 0 && blockIdx.x == 0 && h < 10)
        repack_piece(h, tid, 256, offset_w, deform_w);

    #pragma unroll
    for (int it = 0; it < 4; ++it) {
        int i  = tid + it * 256;
        int c  = i >> 4;
        int p4 = (i & 15) << 2;
        float4 v = *(const float4*)(x + (((size_t)b * CC + c) * HH + h) * WW + w0 + p4);
        s[c][p4 + 0] = v.x; s[c][p4 + 1] = v.y; s[c][p4 + 2] = v.z; s[c][p4 + 3] = v.w;
    }
    __syncthreads();
    #pragma unroll
    for (int it = 0; it < 2; ++it) {
        int j  = tid + it * 256;
        int px = j >> 3;
        int g  = j & 7;
        unsigned int u[4];
        #pragma unroll
        for (int q = 0; q < 4; ++q) {
            __hip_bfloat162 h2 = __float22bfloat162_rn(
                make_float2(s[g * 8 + 2 * q][px], s[g * 8 + 2 * q + 1][px]));
            __builtin_memcpy(&u[q], &h2, 4);
        }
        unsigned short* dst = g_xT + (((size_t)b * HH + h) * WW + w0 + px) * 64 + g * 8;
        *(uint4*)dst = make_uint4(u[0], u[1], u[2], u[3]);
    }
}

// ====== kernel F: fused conv + Y-ext + in-LDS gather (16x16 tile, 4 waves) ======
// Phase-1 restructured: Y-ext loads issued in a batch BEFORE the conv MFMA bulk,
// consumed after it — collapses 16 serial L2 round-trips to ~2.
#define PTF 22
#define NCF 484     // 22*22
#define LDS_SOFF 0      // f32 [18][257] = 18504 B  (phase 2, aliases weights)
#define LDS_SY   18504  // f32 [9][485]  = 17460 B
#define SMEM_F   35968

__global__ __launch_bounds__(256) void conv_gather_fused(
    const float* __restrict__ offset_b,
    const float* __restrict__ deform_w,
    const float* __restrict__ deform_b,
    float* __restrict__ out)
{
    __shared__ __align__(16) unsigned char smem[SMEM_F];
    const int tid = threadIdx.x;

    {   // stage swizzled weights (22784 B)
        const uint4* src = (const uint4*)g_wpack;
        uint4* dst = (uint4*)smem;
        for (int i = tid; i < 1424; i += 256) dst[i] = src[i];
    }
    __syncthreads();

    const int wv = tid >> 6;
    const int l  = tid & 63;
    const int lr = l & 15;
    const int lk = l >> 4;

    const int x0 = blockIdx.x * 16;
    const int y0 = blockIdx.y * 16;
    const int b  = blockIdx.z;
    const unsigned char* xb = (const unsigned char*)(g_xT + (size_t)b * HH * WW * 64);

    const int o1 = (16 + lr > 17) ? 17 : 16 + lr;
    const float bias0 = offset_b[lr];
    const float bias1 = (lr < 2) ? offset_b[16 + lr] : 0.0f;

    f32x4 accC[4][2];
    f32x4 accY[8];
    #pragma unroll
    for (int mi = 0; mi < 4; ++mi)
        #pragma unroll
        for (int reg = 0; reg < 4; ++reg) { accC[mi][0][reg] = bias0; accC[mi][1][reg] = bias1; }
    #pragma unroll
    for (int j = 0; j < 8; ++j) accY[j] = (f32x4){0.f, 0.f, 0.f, 0.f};

    auto ldw = [&](int row, int cbyte) -> bf16x8 {
        unsigned int byte = (unsigned)(row * 128 + cbyte) ^ (((unsigned)(row & 7)) << 4);
        return *(const bf16x8*)(smem + byte);
    };

    // ---------------- phase 1: MFMA (A-frags direct from g_xT) ----------------
    #pragma unroll
    for (int ch = 0; ch < 2; ++ch) {
        const int cbyte = ch * 64 + lk * 16;

        // (1) issue all 8 Y-ext loads up-front (independent, batched in flight)
        bf16x8 ay[8];
        #pragma unroll
        for (int j = 0; j < 8; ++j) {
            const int t = wv + 4 * j;
            int cell = t * 16 + lr; if (cell > NCF - 1) cell = NCF - 1;
            int r = cell / PTF, col = cell - r * PTF;
            int gy = min(max(y0 - 2 + r, 0), HH - 1);
            int gx = min(max(x0 - 2 + col, 0), WW - 1);
            ay[j] = *(const bf16x8*)(xb + (size_t)(gy * WW + gx) * 128 + cbyte);
        }

        // (2) conv MFMA bulk — Y loads land underneath (~1.5k cycles of MFMA)
        #pragma unroll
        for (int kw = 0; kw < 3; ++kw) {
            const int gx = min(x0 + lr + kw, WW - 1);
            bf16x8 a[6];
            #pragma unroll
            for (int rr = 0; rr < 6; ++rr) {
                const int gy = min(y0 + 4 * wv + rr, HH - 1);
                a[rr] = *(const bf16x8*)(xb + (size_t)(gy * WW + gx) * 128 + cbyte);
            }
            #pragma unroll
            for (int kh = 0; kh < 3; ++kh) {
                const int tap = kh * 3 + kw;
                bf16x8 b0 = ldw(tap * 18 + lr, cbyte);
                bf16x8 b1 = ldw(tap * 18 + o1, cbyte);
                #pragma unroll
                for (int mi = 0; mi < 4; ++mi) {
                    accC[mi][0] = __builtin_amdgcn_mfma_f32_16x16x32_bf16(a[mi + kh], b0, accC[mi][0], 0, 0, 0);
                    accC[mi][1] = __builtin_amdgcn_mfma_f32_16x16x32_bf16(a[mi + kh], b1, accC[mi][1], 0, 0, 0);
                }
            }
        }

        // (3) consume the batched Y loads
        {
            unsigned int byY = (unsigned)(lr * 128 + cbyte) ^ (((unsigned)(lr & 7)) << 4);
            bf16x8 bY = *(const bf16x8*)(smem + 20736 + byY);
            #pragma unroll
            for (int j = 0; j < 8; ++j) {
                if (wv + 4 * j < 31)
                    accY[j] = __builtin_amdgcn_mfma_f32_16x16x32_bf16(ay[j], bY, accY[j], 0, 0, 0);
            }
        }
    }

    __syncthreads();   // all weight reads done; arena can be re-used

    // ---------------- phase 2: redistribute to LDS ----------------
    float* s_off = (float*)(smem + LDS_SOFF);   // [18][257]
    float* s_Y   = (float*)(smem + LDS_SY);     // [9][485]
    #pragma unroll
    for (int mi = 0; mi < 4; ++mi) {
        #pragma unroll
        for (int nt = 0; nt < 2; ++nt) {
            const int o = nt * 16 + lr;
            if (o < NOFF) {
                const int pbase = (4 * wv + mi) * 16 + lk * 4;
                #pragma unroll
                for (int reg = 0; reg < 4; ++reg)
                    s_off[o * 257 + pbase + reg] = accC[mi][nt][reg];
            }
        }
    }
    #pragma unroll
    for (int j = 0; j < 8; ++j) {
        const int t = wv + 4 * j;
        if (t < 31 && lr < KK) {
            #pragma unroll
            for (int reg = 0; reg < 4; ++reg) {
                const int cell = t * 16 + lk * 4 + reg;
                if (cell < NCF) {
                    int r = cell / PTF, col = cell - r * PTF;
                    int gy = y0 - 2 + r, gx = x0 - 2 + col;
                    bool inimg = (gy >= 0 && gy < HH && gx >= 0 && gx < WW);
                    s_Y[lr * 485 + cell] = inimg ? accY[j][reg] : 0.0f;
                }
            }
        }
    }
    __syncthreads();

    // ---------------- phase 3: in-LDS bilinear gather ----------------
    const int ty = tid >> 4, tx = tid & 15;
    const int ho = y0 + ty, wo = x0 + tx;
    if (ho >= HO || wo >= WO) return;

    float acc = deform_b[0];

    #pragma unroll
    for (int k = 0; k < KK; ++k) {
        const int kh = k / 3, kw = k % 3;
        float dy = s_off[(2 * k) * 257 + tid];
        float dx = s_off[(2 * k + 1) * 257 + tid];
        float py = (float)(ho + kh) + dy;
        float px = (float)(wo + kw) + dx;
        float y0f = floorf(py), x0f = floorf(px);
        float ly = py - y0f, lx = px - x0f;
        int yi0 = (int)y0f, xi0 = (int)x0f;
        int ry = yi0 - (y0 - 2);
        int rx = xi0 - (x0 - 2);
        float w00 = (1.0f - ly) * (1.0f - lx);
        float w01 = (1.0f - ly) * lx;
        float w10 = ly * (1.0f - lx);
        float w11 = ly * lx;
        float g;
        if ((unsigned)ry <= (unsigned)(PTF - 2) && (unsigned)rx <= (unsigned)(PTF - 2)) {
            const float* tp = s_Y + k * 485;
            const int id = ry * PTF + rx;
            g = w00 * tp[id]       + w01 * tp[id + 1]
              + w10 * tp[id + PTF] + w11 * tp[id + PTF + 1];
        } else {
            // rare fallback: exact bilinear over channels from g_xT
            int yi1 = yi0 + 1, xi1 = xi0 + 1;
            float m00 = (yi0 >= 0 && yi0 < HH && xi0 >= 0 && xi0 < WW) ? w00 : 0.0f;
            float m01 = (yi0 >= 0 && yi0 < HH && xi1 >= 0 && xi1 < WW) ? w01 : 0.0f;
            float m10 = (yi1 >= 0 && yi1 < HH && xi0 >= 0 && xi0 < WW) ? w10 : 0.0f;
            float m11 = (yi1 >= 0 && yi1 < HH && xi1 >= 0 && xi1 < WW) ? w11 : 0.0f;
            int y0c = min(max(yi0, 0), HH - 1), y1c = min(max(yi1, 0), HH - 1);
            int x0c = min(max(xi0, 0), WW - 1), x1c = min(max(xi1, 0), WW - 1);
            const unsigned short* p00 = (const unsigned short*)(xb + (size_t)(y0c * WW + x0c) * 128);
            const unsigned short* p01 = (const unsigned short*)(xb + (size_t)(y0c * WW + x1c) * 128);
            const unsigned short* p10 = (const unsigned short*)(xb + (size_t)(y1c * WW + x0c) * 128);
            const unsigned short* p11 = (const unsigned short*)(xb + (size_t)(y1c * WW + x1c) * 128);
            g = 0.0f;
            for (int c = 0; c < CC; ++c) {
                float gc = m00 * bf2f(p00[c]) + m01 * bf2f(p01[c])
                         + m10 * bf2f(p10[c]) + m11 * bf2f(p11[c]);
                g = fmaf(gc, deform_w[(size_t)c * KK + k], g);
            }
        }
        acc += g;
    }

    out[(size_t)b * NPIX + ho * WO + wo] = acc;
}

extern "C" void kernel_launch(void* const* d_in, const int* in_sizes, int n_in,
                              void* d_out, int out_size, void* d_ws, size_t ws_size,
                              hipStream_t stream) {
    const float* x        = (const float*)d_in[0];
    const float* offset_w = (const float*)d_in[1];
    const float* offset_b = (const float*)d_in[2];
    const float* deform_w = (const float*)d_in[3];
    const float* deform_b = (const float*)d_in[4];
    float* out = (float*)d_out;

    hipLaunchKernelGGL(transpose_kernel, dim3(4, 256, BB), dim3(256), 0, stream,
                       x, offset_w, deform_w);
    hipLaunchKernelGGL(conv_gather_fused, dim3(16, 16, BB), dim3(256), 0, stream,
                       offset_b, deform_w, deform_b, out);
}

// Round 15
// 41.450 us; speedup vs baseline: 1.3841x; 1.3730x over previous
//
#include <hip/hip_runtime.h>
#include <hip/hip_bf16.h>

#define BB 4
#define CC 64
#define HH 256
#define WW 256
#define KK 9
#define NOFF 18
#define HO 254
#define WO 254
#define NPIX (HO*WO)           // 64516

typedef __attribute__((ext_vector_type(8))) short bf16x8;
typedef __attribute__((ext_vector_type(4))) float f32x4;

// ---- cacheable device-global storage ----
// g_wpack: bf16 weights, row-swizzled (conv 20736 + dw 2048), padded to 23552
// g_xT   : bf16 x, layout [B][half][H][W][32ch]  (half = channels 0-31 / 32-63)
__device__ __align__(16) unsigned char  g_wpack[23552];
__device__ __align__(16) unsigned short g_xT[(size_t)BB * 2 * HH * WW * 32];

#define GLB(p)  ((const __attribute__((address_space(1))) void*)(p))
#define LDSP(p) ((__attribute__((address_space(3))) void*)(p))

static __device__ __forceinline__ unsigned short f2bf(float v) {
    __hip_bfloat16 h = __float2bfloat16(v);
    union { __hip_bfloat16 b; unsigned short u; } cv; cv.b = h; return cv.u;
}
static __device__ __forceinline__ float bf2f(unsigned short u) {
    unsigned int w = ((unsigned int)u) << 16;
    float f; __builtin_memcpy(&f, &w, 4); return f;
}

static __device__ __forceinline__ void repack_piece(
    int tap, int tid, int nthr,
    const float* __restrict__ offset_w,
    const float* __restrict__ deform_w)
{
    if (tap < 9) {
        for (int i = tid; i < 18 * 64; i += nthr) {
            int o = i >> 6;
            int c = i & 63;
            int row = tap * 18 + o;
            unsigned int byte = (unsigned)(row * 128 + c * 2) ^ (((unsigned)(row & 7)) << 4);
            *(unsigned short*)(g_wpack + byte) = f2bf(offset_w[((size_t)o * CC + c) * KK + tap]);
        }
    } else {
        for (int i = tid; i < 16 * 64; i += nthr) {
            int t = i >> 6;
            int c = i & 63;
            float v = (t < KK) ? deform_w[(size_t)c * KK + t] : 0.0f;
            unsigned int byte = (unsigned)(t * 128 + c * 2) ^ (((unsigned)(t & 7)) << 4);
            *(unsigned short*)(g_wpack + 20736 + byte) = f2bf(v);
        }
    }
}

// ========== kernel P: x NCHW f32 -> g_xT [B][half][H][W][32] bf16 (+ repack) ==========
__global__ __launch_bounds__(256) void transpose_kernel(
    const float* __restrict__ x,
    const float* __restrict__ offset_w,
    const float* __restrict__ deform_w)
{
    __shared__ float s[64][65];
    const int tid = threadIdx.x;
    const int w0 = blockIdx.x * 64;
    const int h  = blockIdx.y;
    const int b  = blockIdx.z;

    if (b == 0 && blockIdx.x == 0 && h < 10)
        repack_piece(h, tid, 256, offset_w, deform_w);

    #pragma unroll
    for (int it = 0; it < 4; ++it) {
        int i  = tid + it * 256;
        int c  = i >> 4;
        int p4 = (i & 15) << 2;
        float4 v = *(const float4*)(x + (((size_t)b * CC + c) * HH + h) * WW + w0 + p4);
        s[c][p4 + 0] = v.x; s[c][p4 + 1] = v.y; s[c][p4 + 2] = v.z; s[c][p4 + 3] = v.w;
    }
    __syncthreads();
    #pragma unroll
    for (int it = 0; it < 2; ++it) {
        int j  = tid + it * 256;
        int px = j >> 3;
        int g  = j & 7;            // 8-channel group; half = g>>2
        unsigned int u[4];
        #pragma unroll
        for (int q = 0; q < 4; ++q) {
            __hip_bfloat162 h2 = __float22bfloat162_rn(
                make_float2(s[g * 8 + 2 * q][px], s[g * 8 + 2 * q + 1][px]));
            __builtin_memcpy(&u[q], &h2, 4);
        }
        const int half = g >> 2;
        unsigned short* dst = g_xT
            + ((size_t)(b * 2 + half) * HH * WW + (size_t)h * WW + w0 + px) * 32 + (g & 3) * 8;
        *(uint4*)dst = make_uint4(u[0], u[1], u[2], u[3]);
    }
}

// ====== kernel F: fused conv + Y-ext + in-LDS gather, async-DMA staged ======
#define PTF 22
#define NCF 484          // 22*22
#define ROWB 1408        // 22 cells * 64 B (32ch bf16)
#define PATCHB (22*ROWB) // 30976
#define LDS_WP 0         // weights 23552
#define LDS_PATCH 23552
#define SMEM_F (23552 + PATCHB)   // 54528
#define LDS_SOFF 0       // phase-2 alias: f32 [18][257] = 18504
#define LDS_SY   18504   //               f32 [9][485]  = 17460

__global__ __launch_bounds__(256) void conv_gather_fused(
    const float* __restrict__ offset_b,
    const float* __restrict__ deform_w,
    const float* __restrict__ deform_b,
    float* __restrict__ out)
{
    __shared__ __align__(16) unsigned char smem[SMEM_F];
    const int tid = threadIdx.x;
    const int wv = tid >> 6;
    const int l  = tid & 63;
    const int lr = l & 15;
    const int lk = l >> 4;

    const int x0 = blockIdx.x * 16;
    const int y0 = blockIdx.y * 16;
    const int b  = blockIdx.z;

    // ---- async stage: weights (straight copy, content already swizzled) ----
    for (int j = wv; j < 23; j += 4) {
        if (j * 64 + l < 1424)
            __builtin_amdgcn_global_load_lds(GLB(g_wpack + (size_t)j * 1024 + l * 16),
                                             LDSP(smem + LDS_WP + j * 1024), 16, 0, 0);
    }

    // ---- async stage: one channel-half of the 22x22 patch ----
    // LDS linear [cell][64B]; source pre-swizzled so reads use SWZ(lin).
    auto stage_half = [&](int h) {
        const unsigned char* hb = (const unsigned char*)(g_xT + (size_t)(b * 2 + h) * HH * WW * 32);
        for (int r = wv; r < 22; r += 4) {
            const int gy = min(max(y0 - 2 + r, 0), HH - 1);
            const unsigned char* rowbase = hb + (size_t)gy * WW * 64;
            #pragma unroll
            for (int q = 0; q < 2; ++q) {
                const int pl = q * 1024 + (l << 4);
                if (pl < ROWB) {
                    unsigned p = (unsigned)(r * ROWB + pl);
                    unsigned s = (p ^ (((p >> 7) & 7u) << 4)) - (unsigned)(r * ROWB);
                    const int cell   = (int)(s >> 6);
                    const int within = (int)(s & 63u);
                    const int gx = min(max(x0 - 2 + cell, 0), WW - 1);
                    __builtin_amdgcn_global_load_lds(GLB(rowbase + ((size_t)gx << 6) + within),
                                                     LDSP(smem + LDS_PATCH + r * ROWB + q * 1024),
                                                     16, 0, 0);
                }
            }
        }
    };

    const int o1 = (16 + lr > 17) ? 17 : 16 + lr;
    const float bias0 = offset_b[lr];
    const float bias1 = (lr < 2) ? offset_b[16 + lr] : 0.0f;

    f32x4 accC[4][2];
    f32x4 accY[8];
    #pragma unroll
    for (int mi = 0; mi < 4; ++mi)
        #pragma unroll
        for (int reg = 0; reg < 4; ++reg) { accC[mi][0][reg] = bias0; accC[mi][1][reg] = bias1; }
    #pragma unroll
    for (int j = 0; j < 8; ++j) accY[j] = (f32x4){0.f, 0.f, 0.f, 0.f};

    auto ldw = [&](int row, int cbyte) -> bf16x8 {
        unsigned int byte = (unsigned)(row * 128 + cbyte) ^ (((unsigned)(row & 7)) << 4);
        return *(const bf16x8*)(smem + LDS_WP + byte);
    };
    auto lda = [&](int cell) -> bf16x8 {
        unsigned lin = (unsigned)(cell * 64 + lk * 16);
        lin ^= ((lin >> 7) & 7u) << 4;
        return *(const bf16x8*)(smem + LDS_PATCH + lin);
    };

    auto mfma_half = [&](int h) {
        const int cbyte = h * 64 + lk * 16;
        #pragma unroll
        for (int kw = 0; kw < 3; ++kw) {
            #pragma unroll
            for (int kh = 0; kh < 3; ++kh) {
                const int tap = kh * 3 + kw;
                bf16x8 b0 = ldw(tap * 18 + lr, cbyte);
                bf16x8 b1 = ldw(tap * 18 + o1, cbyte);
                #pragma unroll
                for (int mi = 0; mi < 4; ++mi) {
                    const int cell = (4 * wv + mi + kh + 2) * PTF + (lr + kw + 2);
                    bf16x8 a = lda(cell);
                    accC[mi][0] = __builtin_amdgcn_mfma_f32_16x16x32_bf16(a, b0, accC[mi][0], 0, 0, 0);
                    accC[mi][1] = __builtin_amdgcn_mfma_f32_16x16x32_bf16(a, b1, accC[mi][1], 0, 0, 0);
                }
            }
        }
        {
            unsigned int byY = (unsigned)(lr * 128 + cbyte) ^ (((unsigned)(lr & 7)) << 4);
            bf16x8 bY = *(const bf16x8*)(smem + LDS_WP + 20736 + byY);
            #pragma unroll
            for (int j = 0; j < 8; ++j) {
                const int t = wv + 4 * j;
                if (t < 31) {
                    int cell = t * 16 + lr; if (cell > NCF - 1) cell = NCF - 1;
                    bf16x8 a = lda(cell);
                    accY[j] = __builtin_amdgcn_mfma_f32_16x16x32_bf16(a, bY, accY[j], 0, 0, 0);
                }
            }
        }
    };

    // ---- pipeline: DMA half0 -> compute half0 -> DMA half1 -> compute half1 ----
    stage_half(0);
    __syncthreads();          // vmcnt(0) drain + barrier: weights + half0 visible
    mfma_half(0);
    __syncthreads();          // all half0 reads done
    stage_half(1);
    __syncthreads();          // half1 visible
    mfma_half(1);
    __syncthreads();          // all reads done; arena re-usable

    // ---------------- phase 2: redistribute to LDS ----------------
    float* s_off = (float*)(smem + LDS_SOFF);   // [18][257]
    float* s_Y   = (float*)(smem + LDS_SY);     // [9][485]
    #pragma unroll
    for (int mi = 0; mi < 4; ++mi) {
        #pragma unroll
        for (int nt = 0; nt < 2; ++nt) {
            const int o = nt * 16 + lr;
            if (o < NOFF) {
                const int pbase = (4 * wv + mi) * 16 + lk * 4;
                #pragma unroll
                for (int reg = 0; reg < 4; ++reg)
                    s_off[o * 257 + pbase + reg] = accC[mi][nt][reg];
            }
        }
    }
    #pragma unroll
    for (int j = 0; j < 8; ++j) {
        const int t = wv + 4 * j;
        if (t < 31 && lr < KK) {
            #pragma unroll
            for (int reg = 0; reg < 4; ++reg) {
                const int cell = t * 16 + lk * 4 + reg;
                if (cell < NCF) {
                    int r = cell / PTF, col = cell - r * PTF;
                    int gy = y0 - 2 + r, gx = x0 - 2 + col;
                    bool inimg = (gy >= 0 && gy < HH && gx >= 0 && gx < WW);
                    s_Y[lr * 485 + cell] = inimg ? accY[j][reg] : 0.0f;
                }
            }
        }
    }
    __syncthreads();

    // ---------------- phase 3: in-LDS bilinear gather ----------------
    const int ty = tid >> 4, tx = tid & 15;
    const int ho = y0 + ty, wo = x0 + tx;
    if (ho >= HO || wo >= WO) return;

    float acc = deform_b[0];

    #pragma unroll
    for (int k = 0; k < KK; ++k) {
        const int kh = k / 3, kw = k % 3;
        float dy = s_off[(2 * k) * 257 + tid];
        float dx = s_off[(2 * k + 1) * 257 + tid];
        float py = (float)(ho + kh) + dy;
        float px = (float)(wo + kw) + dx;
        float y0f = floorf(py), x0f = floorf(px);
        float ly = py - y0f, lx = px - x0f;
        int yi0 = (int)y0f, xi0 = (int)x0f;
        int ry = yi0 - (y0 - 2);
        int rx = xi0 - (x0 - 2);
        float w00 = (1.0f - ly) * (1.0f - lx);
        float w01 = (1.0f - ly) * lx;
        float w10 = ly * (1.0f - lx);
        float w11 = ly * lx;
        float g;
        if ((unsigned)ry <= (unsigned)(PTF - 2) && (unsigned)rx <= (unsigned)(PTF - 2)) {
            const float* tp = s_Y + k * 485;
            const int id = ry * PTF + rx;
            g = w00 * tp[id]       + w01 * tp[id + 1]
              + w10 * tp[id + PTF] + w11 * tp[id + PTF + 1];
        } else {
            // rare fallback: exact bilinear over channels from g_xT (both halves)
            int yi1 = yi0 + 1, xi1 = xi0 + 1;
            float m00 = (yi0 >= 0 && yi0 < HH && xi0 >= 0 && xi0 < WW) ? w00 : 0.0f;
            float m01 = (yi0 >= 0 && yi0 < HH && xi1 >= 0 && xi1 < WW) ? w01 : 0.0f;
            float m10 = (yi1 >= 0 && yi1 < HH && xi0 >= 0 && xi0 < WW) ? w10 : 0.0f;
            float m11 = (yi1 >= 0 && yi1 < HH && xi1 >= 0 && xi1 < WW) ? w11 : 0.0f;
            int y0c = min(max(yi0, 0), HH - 1), y1c = min(max(yi1, 0), HH - 1);
            int x0c = min(max(xi0, 0), WW - 1), x1c = min(max(xi1, 0), WW - 1);
            g = 0.0f;
            #pragma unroll
            for (int h = 0; h < 2; ++h) {
                const unsigned short* xh = g_xT + (size_t)(b * 2 + h) * HH * WW * 32;
                const unsigned short* p00 = xh + (size_t)(y0c * WW + x0c) * 32;
                const unsigned short* p01 = xh + (size_t)(y0c * WW + x1c) * 32;
                const unsigned short* p10 = xh + (size_t)(y1c * WW + x0c) * 32;
                const unsigned short* p11 = xh + (size_t)(y1c * WW + x1c) * 32;
                for (int c = 0; c < 32; ++c) {
                    float gc = m00 * bf2f(p00[c]) + m01 * bf2f(p01[c])
                             + m10 * bf2f(p10[c]) + m11 * bf2f(p11[c]);
                    g = fmaf(gc, deform_w[(size_t)(h * 32 + c) * KK + k], g);
                }
            }
        }
        acc += g;
    }

    out[(size_t)b * NPIX + ho * WO + wo] = acc;
}

extern "C" void kernel_launch(void* const* d_in, const int* in_sizes, int n_in,
                              void* d_out, int out_size, void* d_ws, size_t ws_size,
                              hipStream_t stream) {
    const float* x        = (const float*)d_in[0];
    const float* offset_w = (const float*)d_in[1];
    const float* offset_b = (const float*)d_in[2];
    const float* deform_w = (const float*)d_in[3];
    const float* deform_b = (const float*)d_in[4];
    float* out = (float*)d_out;

    hipLaunchKernelGGL(transpose_kernel, dim3(4, 256, BB), dim3(256), 0, stream,
                       x, offset_w, deform_w);
    hipLaunchKernelGGL(conv_gather_fused, dim3(16, 16, BB), dim3(256), 0, stream,
                       offset_b, deform_w, deform_b, out);
}